// Round 8
// baseline (56.740 us; speedup 1.0000x reference)
//
#include <hip/hip_runtime.h>

// GraphSearchPolicy fused kernel, DS-offloaded broadcasts. MI355X gfx950.
// B=2048, A=256, DE=128, DH=256, DR=128, DIN=512, ACT=256, NR=1000.
// Grid 256 x 512 thr (BB=8, 1 block/CU). Broadcast operands (x, h, x2) are
// read at wave-uniform GLOBAL addresses (1 L1 line / instr, or SMEM) instead
// of LDS: kills the ~19us/CU ds_read_b128 serialization of R5.
// LDS holds only per-lane-distinct data: split-K partials + score table.
// h/x2 are staged in the block's own dist_out rows (overwritten at the end).

#define DE   128
#define DH   256
#define DR   128
#define DIN  512
#define ACT  256
#define AA   256
#define BB   8
#define NR   1000

// ---------------------------------------------------------------- transpose
__global__ __launch_bounds__(1024) void transpose_kernel(
    const float* __restrict__ rel_emb, float* __restrict__ rel_embT)
{
    __shared__ float ldsT[128 * 9];
    const int t  = threadIdx.x;
    const int r0 = blockIdx.x * 8;
    {
        const int row = t >> 7;          // 0..7
        const int k   = t & 127;
        ldsT[k * 9 + row] = rel_emb[(size_t)(r0 + row) * DR + k];
    }
    __syncthreads();
    {
        const int k = t >> 3;            // 0..127
        const int j = t & 7;
        rel_embT[(size_t)k * NR + r0 + j] = ldsT[k * 9 + j];
    }
}

// ---------------------------------------------------------------- main
__global__ __launch_bounds__(512, 2) void policy_kernel(
    const int*   __restrict__ e,
    const int*   __restrict__ q,
    const float* __restrict__ H,
    const int*   __restrict__ r_space,
    const float* __restrict__ r_mask,
    const float* __restrict__ entity_emb,
    const float* __restrict__ rel_emb,
    const float* __restrict__ W1,
    const float* __restrict__ b1,
    const float* __restrict__ W2,
    const float* __restrict__ b2,
    const float* __restrict__ rel_embT,
    float* __restrict__ dist_out,
    float* __restrict__ ent_out)
{
    const int t  = threadIdx.x;          // 0..511
    const int b0 = blockIdx.x * BB;

    __shared__ __align__(16) float part[8 * BB * ACT];  // 64 KB (reused L1/L2)
    __shared__ float scoreL[BB * NR];                   // 31.25 KB
    __shared__ float wredM[8][4], wredS[8][4], wredL[8][4];

    // Block-private global scratch = this block's dist_out rows (8 KB).
    // Timeline: h[k][row] (combine1..layer2) -> x2[k][row] (combine2..score)
    // -> final dist values. Barriers separate each use.
    float* sc = dist_out + (size_t)b0 * AA;

    // ---- early loads: action indices + masks + row ids ----
    const int a   = t & 255;
    const int rp  = t >> 8;              // 0..1
    const int rp4 = rp * 4;              // rows rp4..rp4+3
    int   ridx[4];
    float msk [4];
    #pragma unroll
    for (int j = 0; j < 4; ++j) {
        ridx[j] = r_space[(size_t)(b0 + rp4 + j) * AA + a];
        msk [j] = r_mask [(size_t)(b0 + rp4 + j) * AA + a];
    }
    int eb[8], qb[8];
    #pragma unroll
    for (int j = 0; j < 8; ++j) { eb[j] = e[b0 + j]; qb[j] = q[b0 + j]; }

    // ---- layer 1 partials: wave ks owns k-slice [ks*64,+64), thread col-quad.
    //      x read straight from tables at wave-uniform addresses. ----
    {
        const int cq = (t & 63) * 4;
        const int ks = t >> 6;           // 0..7
        const int k0 = ks * 64;
        const float* bp[8];
        if (k0 < DE) {
            #pragma unroll
            for (int j = 0; j < 8; ++j) bp[j] = entity_emb + (size_t)eb[j] * DE + k0;
        } else if (k0 < DE + DH) {
            #pragma unroll
            for (int j = 0; j < 8; ++j) bp[j] = H + (size_t)(b0 + j) * DH + (k0 - DE);
        } else {
            #pragma unroll
            for (int j = 0; j < 8; ++j) bp[j] = rel_emb + (size_t)qb[j] * DR + (k0 - DE - DH);
        }
        float4 acc[8];
        #pragma unroll
        for (int j = 0; j < 8; ++j) acc[j] = make_float4(0.f, 0.f, 0.f, 0.f);
        const float* wbase = W1 + (size_t)k0 * ACT + cq;
        #pragma unroll 4
        for (int k4 = 0; k4 < 64; k4 += 4) {
            float4 xr[8];
            #pragma unroll
            for (int j = 0; j < 8; ++j) xr[j] = *(const float4*)(bp[j] + k4);  // uniform
            #pragma unroll
            for (int i = 0; i < 4; ++i) {
                const float4 w = *(const float4*)(wbase + (size_t)(k4 + i) * ACT);
                #pragma unroll
                for (int j = 0; j < 8; ++j) {
                    const float xv = ((const float*)&xr[j])[i];   // static extract
                    acc[j].x = fmaf(w.x, xv, acc[j].x);
                    acc[j].y = fmaf(w.y, xv, acc[j].y);
                    acc[j].z = fmaf(w.z, xv, acc[j].z);
                    acc[j].w = fmaf(w.w, xv, acc[j].w);
                }
            }
        }
        float* pb = &part[(size_t)(ks * BB) * ACT + cq];
        #pragma unroll
        for (int j = 0; j < 8; ++j)
            *(float4*)(pb + (size_t)j * ACT) = acc[j];            // conflict-free
    }
    __syncthreads();

    // ---- combine1 + bias + ReLU -> sc[k][row] (global scratch, h) ----
    #pragma unroll
    for (int i = 0; i < 4; ++i) {
        const int o   = t + i * 512;     // 0..2047
        const int row = o >> 8;
        const int col = o & 255;         // h index k
        float s = b1[col];
        #pragma unroll
        for (int ks = 0; ks < 8; ++ks)
            s += part[(ks * BB + row) * ACT + col];               // conflict-free
        sc[col * BB + row] = fmaxf(s, 0.f);
    }
    __syncthreads();                     // drains stores: h visible to all waves

    // ---- layer 2 partials: wave ks2 owns [ks2*32,+32), thread col-pair.
    //      h via wave-uniform float4 reads from sc (L1-hot). ----
    {
        const int cp  = (t & 63) * 2;
        const int ks2 = t >> 6;
        const int k0  = ks2 * 32;
        float2 acc[8];
        #pragma unroll
        for (int j = 0; j < 8; ++j) acc[j] = make_float2(0.f, 0.f);
        #pragma unroll 4
        for (int kk = 0; kk < 32; ++kk) {
            const int k = k0 + kk;
            const float2 w  = *(const float2*)&W2[(size_t)k * DR + cp];
            const float4 ha = *(const float4*)&sc[k * BB];        // rows 0-3 (uniform)
            const float4 hb = *(const float4*)&sc[k * BB + 4];    // rows 4-7
            acc[0].x = fmaf(w.x, ha.x, acc[0].x); acc[0].y = fmaf(w.y, ha.x, acc[0].y);
            acc[1].x = fmaf(w.x, ha.y, acc[1].x); acc[1].y = fmaf(w.y, ha.y, acc[1].y);
            acc[2].x = fmaf(w.x, ha.z, acc[2].x); acc[2].y = fmaf(w.y, ha.z, acc[2].y);
            acc[3].x = fmaf(w.x, ha.w, acc[3].x); acc[3].y = fmaf(w.y, ha.w, acc[3].y);
            acc[4].x = fmaf(w.x, hb.x, acc[4].x); acc[4].y = fmaf(w.y, hb.x, acc[4].y);
            acc[5].x = fmaf(w.x, hb.y, acc[5].x); acc[5].y = fmaf(w.y, hb.y, acc[5].y);
            acc[6].x = fmaf(w.x, hb.z, acc[6].x); acc[6].y = fmaf(w.y, hb.z, acc[6].y);
            acc[7].x = fmaf(w.x, hb.w, acc[7].x); acc[7].y = fmaf(w.y, hb.w, acc[7].y);
        }
        float* pb = &part[(size_t)(ks2 * BB) * DR + cp];
        #pragma unroll
        for (int j = 0; j < 8; ++j)
            *(float2*)(pb + (size_t)j * DR) = acc[j];
    }
    __syncthreads();

    // ---- combine2 + bias -> sc[k][row] (x2; overwrites dead h k<128) ----
    #pragma unroll
    for (int i = 0; i < 2; ++i) {
        const int o   = t + i * 512;     // 0..1023
        const int row = o >> 7;
        const int col = o & 127;         // x2 index k
        float s = b2[col];
        #pragma unroll
        for (int ks = 0; ks < 8; ++ks)
            s += part[(ks * BB + row) * DR + col];
        sc[col * BB + row] = s;
    }
    __syncthreads();                     // x2 visible

    // ---- score GEMM: scoreL[row][r] = sum_k x2[k][row] * rel_embT[k][r] ----
    {
        const int r0  = t;
        const int r1  = t + 512;
        const bool v1 = (r1 < NR);
        const int r1c = v1 ? r1 : (NR - 1);
        float acc0[8], acc1[8];
        #pragma unroll
        for (int j = 0; j < 8; ++j) { acc0[j] = 0.f; acc1[j] = 0.f; }
        #pragma unroll 2
        for (int k4 = 0; k4 < DR; k4 += 4) {
            float4 xa[4], xb[4];
            #pragma unroll
            for (int i = 0; i < 4; ++i) {
                xa[i] = *(const float4*)&sc[(k4 + i) * BB];       // uniform bcast
                xb[i] = *(const float4*)&sc[(k4 + i) * BB + 4];
            }
            #pragma unroll
            for (int i = 0; i < 4; ++i) {
                const float w0 = rel_embT[(size_t)(k4 + i) * NR + r0];   // coalesced
                const float w1 = rel_embT[(size_t)(k4 + i) * NR + r1c];
                acc0[0] = fmaf(w0, xa[i].x, acc0[0]); acc1[0] = fmaf(w1, xa[i].x, acc1[0]);
                acc0[1] = fmaf(w0, xa[i].y, acc0[1]); acc1[1] = fmaf(w1, xa[i].y, acc1[1]);
                acc0[2] = fmaf(w0, xa[i].z, acc0[2]); acc1[2] = fmaf(w1, xa[i].z, acc1[2]);
                acc0[3] = fmaf(w0, xa[i].w, acc0[3]); acc1[3] = fmaf(w1, xa[i].w, acc1[3]);
                acc0[4] = fmaf(w0, xb[i].x, acc0[4]); acc1[4] = fmaf(w1, xb[i].x, acc1[4]);
                acc0[5] = fmaf(w0, xb[i].y, acc0[5]); acc1[5] = fmaf(w1, xb[i].y, acc1[5]);
                acc0[6] = fmaf(w0, xb[i].z, acc0[6]); acc1[6] = fmaf(w1, xb[i].z, acc1[6]);
                acc0[7] = fmaf(w0, xb[i].w, acc0[7]); acc1[7] = fmaf(w1, xb[i].w, acc1[7]);
            }
        }
        #pragma unroll
        for (int j = 0; j < 8; ++j) scoreL[j * NR + r0] = acc0[j];
        if (v1) {
            #pragma unroll
            for (int j = 0; j < 8; ++j) scoreL[j * NR + r1] = acc1[j];
        }
    }
    __syncthreads();

    // ---- logits: 4-byte LDS lookups for this thread's 4 rows ----
    float lg[4];
    #pragma unroll
    for (int j = 0; j < 4; ++j)
        lg[j] = scoreL[(rp4 + j) * NR + ridx[j]] - (1.0f - msk[j]) * 1e31f;

    const int wv = t >> 6;               // waves 0..3: rows 0-3; 4..7: rows 4-7

    // ---- max ----
    float m[4];
    #pragma unroll
    for (int j = 0; j < 4; ++j) m[j] = lg[j];
    #pragma unroll
    for (int off = 32; off >= 1; off >>= 1) {
        #pragma unroll
        for (int j = 0; j < 4; ++j)
            m[j] = fmaxf(m[j], __shfl_xor(m[j], off, 64));
    }
    if ((t & 63) == 0) {
        #pragma unroll
        for (int j = 0; j < 4; ++j) wredM[wv][j] = m[j];
    }
    __syncthreads();
    {
        const int wb = rp * 4;
        #pragma unroll
        for (int j = 0; j < 4; ++j)
            m[j] = fmaxf(fmaxf(wredM[wb][j], wredM[wb+1][j]),
                         fmaxf(wredM[wb+2][j], wredM[wb+3][j]));
    }

    // ---- exp + joint sums S, SL = sum p*(lg-m) ----
    float p[4], s[4], sl[4];
    #pragma unroll
    for (int j = 0; j < 4; ++j) {
        const float z = lg[j] - m[j];
        p[j]  = __expf(z);
        s[j]  = p[j];
        sl[j] = p[j] * z;
    }
    #pragma unroll
    for (int off = 32; off >= 1; off >>= 1) {
        #pragma unroll
        for (int j = 0; j < 4; ++j) {
            s[j]  += __shfl_xor(s[j],  off, 64);
            sl[j] += __shfl_xor(sl[j], off, 64);
        }
    }
    if ((t & 63) == 0) {
        #pragma unroll
        for (int j = 0; j < 4; ++j) { wredS[wv][j] = s[j]; wredL[wv][j] = sl[j]; }
    }
    __syncthreads();
    float S[4], SL[4];
    {
        const int wb = rp * 4;
        #pragma unroll
        for (int j = 0; j < 4; ++j) {
            S [j] = wredS[wb][j] + wredS[wb+1][j] + wredS[wb+2][j] + wredS[wb+3][j];
            SL[j] = wredL[wb][j] + wredL[wb+1][j] + wredL[wb+2][j] + wredL[wb+3][j];
        }
    }

    // ---- outputs (overwrite scratch with final dist) ----
    #pragma unroll
    for (int j = 0; j < 4; ++j)
        dist_out[(size_t)(b0 + rp4 + j) * AA + a] = p[j] / S[j];
    if (t == 0) {
        #pragma unroll
        for (int j = 0; j < 4; ++j)
            ent_out[b0 + j] = __logf(S[j]) - SL[j] / S[j];
    }
    if (t == 256) {
        #pragma unroll
        for (int j = 0; j < 4; ++j)
            ent_out[b0 + 4 + j] = __logf(S[j]) - SL[j] / S[j];
    }
}

extern "C" void kernel_launch(void* const* d_in, const int* in_sizes, int n_in,
                              void* d_out, int out_size, void* d_ws, size_t ws_size,
                              hipStream_t stream) {
    const int*   e          = (const int*)  d_in[0];
    const int*   q          = (const int*)  d_in[1];
    const float* H          = (const float*)d_in[2];
    const int*   r_space    = (const int*)  d_in[3];
    const float* r_mask     = (const float*)d_in[4];
    const float* entity_emb = (const float*)d_in[5];
    const float* rel_emb    = (const float*)d_in[6];
    const float* W1         = (const float*)d_in[7];
    const float* b1         = (const float*)d_in[8];
    const float* W2         = (const float*)d_in[9];
    const float* b2         = (const float*)d_in[10];

    const int B = in_sizes[0];              // 2048
    float* dist_out = (float*)d_out;                    // [B, 256]
    float* ent_out  = (float*)d_out + (size_t)B * AA;   // [B]
    float* rel_embT = (float*)d_ws;                     // [128][1000] = 512 KB

    transpose_kernel<<<NR / 8, 1024, 0, stream>>>(rel_emb, rel_embT);
    policy_kernel<<<B / BB, 512, 0, stream>>>(
        e, q, H, r_space, r_mask, entity_emb, rel_emb,
        W1, b1, W2, b2, rel_embT, dist_out, ent_out);
}

// Round 9
// 33.594 us; speedup vs baseline: 1.6890x; 1.6890x over previous
//
#include <hip/hip_runtime.h>

// GraphSearchPolicy, MFMA formulation. MI355X gfx950.
// B=2048, A=256, DE=128, DH=256, DR=128, DIN=512, ACT=256, NR=1000.
//
// Three chained GEMMs per 8-row block, all via mfma_f32_16x16x32_bf16:
//   L1: [8x512]@[512x256]  -> h     (A = X hi/lo split, B = W1 bf16)
//   L2: [8x256]@[256x128]  -> x2    (A = h hi/lo split, B = W2 bf16)
//   SC: [8x128]@[128x1008] -> score (A = x2 hi/lo split, B = rel^T bf16)
// prep_kernel pre-packs B operands into MFMA B-fragment layout in d_ws.
// A and B fragments use the SAME (lane,reg)->k formula, so any k-slot
// permutation in the HW mapping cancels (dot is k-permutation invariant).
// C mapping (HW-verified): col = lane&15, row = (lane>>4)*4 + reg.

#define DE   128
#define DH   256
#define DR   128
#define DIN  512
#define ACT  256
#define AA   256
#define BB   8
#define NR   1000
#define SL   1008            // padded score width (63 n-tiles)

#define XS_P 520             // xs row stride (pad)
#define HS_P 264             // hs row stride
#define X2_P 136             // x2 row stride

#define W2B_OFF 16384        // uint4 offsets into d_ws
#define RB_OFF  20480
#define PREP_T  36608        // total prep threads (572 tiles * 64)

typedef __attribute__((ext_vector_type(4))) float f32x4;
typedef __attribute__((ext_vector_type(8))) short s16x8;
typedef unsigned int u32;

#define MFMA(a,b,c) __builtin_amdgcn_mfma_f32_16x16x32_bf16(a, b, c, 0, 0, 0)

__device__ __forceinline__ u32 b16(float x) {            // fp32 -> bf16 (RNE)
    u32 u = __float_as_uint(x);
    return (u + 0x7FFFu + ((u >> 16) & 1u)) >> 16;
}
__device__ __forceinline__ float b16f(u32 h) { return __uint_as_float(h << 16); }
__device__ __forceinline__ u32 pack2(float a, float b) { return b16(a) | (b16(b) << 16); }

__device__ __forceinline__ s16x8 asfrag(uint4 v) {
    union { uint4 u; s16x8 s; } c; c.u = v; return c.s;
}

// 8 consecutive fp32 (16B aligned) -> hi/lo bf16 A-fragments
__device__ __forceinline__ void build_frags(const float* p, uint4& hi, uint4& lo) {
    const float4 a = *(const float4*)p;
    const float4 b = *(const float4*)(p + 4);
    const float f[8] = {a.x, a.y, a.z, a.w, b.x, b.y, b.z, b.w};
    u32 h[8]; float r[8];
    #pragma unroll
    for (int i = 0; i < 8; ++i) { h[i] = b16(f[i]); r[i] = f[i] - b16f(h[i]); }
    hi.x = h[0] | (h[1] << 16); hi.y = h[2] | (h[3] << 16);
    hi.z = h[4] | (h[5] << 16); hi.w = h[6] | (h[7] << 16);
    lo.x = pack2(r[0], r[1]);   lo.y = pack2(r[2], r[3]);
    lo.z = pack2(r[4], r[5]);   lo.w = pack2(r[6], r[7]);
}

// ---------------------------------------------------------------- prep
// Packs W1 [512x256], W2 [256x128], rel_emb^T [128x1008] into bf16
// B-fragment tiles: value reg v of lane l in tile (kt,nt) covers
// n = nt*16 + (l&15), k = kt*32 + (l>>4)*8 + {2v, 2v+1}.
__global__ __launch_bounds__(256) void prep_kernel(
    const float* __restrict__ W1, const float* __restrict__ W2,
    const float* __restrict__ rel_emb, uint4* __restrict__ wsb)
{
    const int id = blockIdx.x * 256 + threadIdx.x;       // 0..36607
    const int l  = id & 63;
    const int tl = id >> 6;                              // tile 0..571
    const int kb_l = (l >> 4) * 8;
    const int n_l  = l & 15;
    float f[8];
    if (tl < 256) {                                      // W1B: tl = kt*16+nt
        const int kt = tl >> 4, nt = tl & 15;
        const int kb = kt * 32 + kb_l, n = nt * 16 + n_l;
        #pragma unroll
        for (int e = 0; e < 8; ++e) f[e] = W1[(size_t)(kb + e) * ACT + n];
    } else if (tl < 320) {                               // W2B: tl-256 = kt*8+nt
        const int t2 = tl - 256;
        const int kt = t2 >> 3, nt = t2 & 7;
        const int kb = kt * 32 + kb_l, n = nt * 16 + n_l;
        #pragma unroll
        for (int e = 0; e < 8; ++e) f[e] = W2[(size_t)(kb + e) * DR + n];
    } else {                                             // RB: tl-320 = nt*4+kt
        const int t3 = tl - 320;                         // 0..251
        const int nt = t3 >> 2, kt = t3 & 3;
        const int kb = kt * 32 + kb_l, n = nt * 16 + n_l; // n = relation id
        #pragma unroll
        for (int e = 0; e < 8; ++e)
            f[e] = (n < NR) ? rel_emb[(size_t)n * DR + kb + e] : 0.f;
    }
    uint4 o;
    o.x = pack2(f[0], f[1]); o.y = pack2(f[2], f[3]);
    o.z = pack2(f[4], f[5]); o.w = pack2(f[6], f[7]);
    wsb[id] = o;
}

// ---------------------------------------------------------------- main
__global__ __launch_bounds__(512, 2) void policy_kernel(
    const int*   __restrict__ e,
    const int*   __restrict__ q,
    const float* __restrict__ H,
    const int*   __restrict__ r_space,
    const float* __restrict__ r_mask,
    const float* __restrict__ entity_emb,
    const float* __restrict__ rel_emb,
    const float* __restrict__ b1,
    const float* __restrict__ b2,
    const uint4* __restrict__ wsb,
    float* __restrict__ dist_out,
    float* __restrict__ ent_out)
{
    const int t  = threadIdx.x;          // 0..511
    const int b0 = blockIdx.x * BB;
    const int l  = t & 63;
    const int w  = t >> 6;               // wave 0..7
    const int m  = l & 15;               // fragment row
    const bool mval = (m < 8);
    const int kb_l = (l >> 4) * 8;

    __shared__ __align__(16) float xs[BB * XS_P];    // 16.6 KB input rows
    __shared__ __align__(16) float hs[BB * HS_P];    //  8.4 KB hidden
    __shared__ __align__(16) float x2s[BB * X2_P];   //  4.3 KB x2
    __shared__ float scoreL[BB * SL];                // 31.5 KB scores
    __shared__ float wredM[8][4], wredS[8][4], wredL[8][4];

    // ---- early loads: action indices + masks ----
    const int a   = t & 255;
    const int rp  = t >> 8;              // 0..1
    const int rp4 = rp * 4;
    int   ridx[4];
    float msk [4];
    #pragma unroll
    for (int j = 0; j < 4; ++j) {
        ridx[j] = r_space[(size_t)(b0 + rp4 + j) * AA + a];
        msk [j] = r_mask [(size_t)(b0 + rp4 + j) * AA + a];
    }

    // ---- stage X = concat(E,H,Q) fp32 -> xs[row][k] ----
    {
        const int srow = t & 7;
        const int scol = t >> 3;         // 0..63
        const int sb   = b0 + srow;
        const int eb   = e[sb];
        const int qb   = q[sb];
        #pragma unroll
        for (int rnd = 0; rnd < 8; ++rnd) {
            const int k = rnd * 64 + scol;
            float v;
            if (k < DE)            v = entity_emb[(size_t)eb * DE + k];
            else if (k < DE + DH)  v = H[(size_t)sb * DH + (k - DE)];
            else                   v = rel_emb[(size_t)qb * DR + (k - DE - DH)];
            xs[srow * XS_P + k] = v;
        }
    }
    __syncthreads();

    // ---- layer 1: wave owns n-tiles {2w, 2w+1}; K loop inside wave ----
    {
        f32x4 acc0 = {0.f, 0.f, 0.f, 0.f};
        f32x4 acc1 = {0.f, 0.f, 0.f, 0.f};
        const int nt0 = 2 * w, nt1 = 2 * w + 1;
        #pragma unroll 4
        for (int kt = 0; kt < 16; ++kt) {
            uint4 ahi = {0,0,0,0}, alo = {0,0,0,0};
            if (mval) build_frags(&xs[m * XS_P + kt * 32 + kb_l], ahi, alo);
            const uint4 bv0 = wsb[(size_t)(kt * 16 + nt0) * 64 + l];
            const uint4 bv1 = wsb[(size_t)(kt * 16 + nt1) * 64 + l];
            acc0 = MFMA(asfrag(ahi), asfrag(bv0), acc0);
            acc0 = MFMA(asfrag(alo), asfrag(bv0), acc0);
            acc1 = MFMA(asfrag(ahi), asfrag(bv1), acc1);
            acc1 = MFMA(asfrag(alo), asfrag(bv1), acc1);
        }
        if (l < 32) {                    // C: row=(l>>4)*4+v (0..7), col=l&15
            const int r4 = (l >> 4) * 4;
            const int n0 = nt0 * 16 + m, n1 = nt1 * 16 + m;
            const float bb0 = b1[n0], bb1 = b1[n1];
            #pragma unroll
            for (int v = 0; v < 4; ++v) {
                hs[(r4 + v) * HS_P + n0] = fmaxf(acc0[v] + bb0, 0.f);
                hs[(r4 + v) * HS_P + n1] = fmaxf(acc1[v] + bb1, 0.f);
            }
        }
    }
    __syncthreads();

    // ---- layer 2: wave owns n-tile w ----
    {
        f32x4 acc = {0.f, 0.f, 0.f, 0.f};
        #pragma unroll 4
        for (int kt = 0; kt < 8; ++kt) {
            uint4 ahi = {0,0,0,0}, alo = {0,0,0,0};
            if (mval) build_frags(&hs[m * HS_P + kt * 32 + kb_l], ahi, alo);
            const uint4 bv = wsb[(size_t)(W2B_OFF + (kt * 8 + w) * 64 + l)];
            acc = MFMA(asfrag(ahi), asfrag(bv), acc);
            acc = MFMA(asfrag(alo), asfrag(bv), acc);
        }
        if (l < 32) {
            const int r4 = (l >> 4) * 4;
            const int n  = w * 16 + m;
            const float bb = b2[n];
            #pragma unroll
            for (int v = 0; v < 4; ++v)
                x2s[(r4 + v) * X2_P + n] = acc[v] + bb;
        }
    }
    __syncthreads();

    // ---- score: A-frags (x2) built once; wave owns 8 n-tiles ----
    {
        uint4 shi[4], slo[4];
        #pragma unroll
        for (int kt = 0; kt < 4; ++kt) {
            shi[kt] = (uint4){0,0,0,0}; slo[kt] = (uint4){0,0,0,0};
            if (mval) build_frags(&x2s[m * X2_P + kt * 32 + kb_l], shi[kt], slo[kt]);
        }
        #pragma unroll 2
        for (int i = 0; i < 8; ++i) {
            const int nt = w * 8 + i;
            if (nt >= 63) break;         // wave 7 does 7 tiles (uniform branch)
            f32x4 acc = {0.f, 0.f, 0.f, 0.f};
            #pragma unroll
            for (int kt = 0; kt < 4; ++kt) {
                const uint4 bv = wsb[(size_t)(RB_OFF + (nt * 4 + kt) * 64 + l)];
                acc = MFMA(asfrag(shi[kt]), asfrag(bv), acc);
                acc = MFMA(asfrag(slo[kt]), asfrag(bv), acc);
            }
            if (l < 32) {
                const int r4 = (l >> 4) * 4;
                const int n  = nt * 16 + m;
                #pragma unroll
                for (int v = 0; v < 4; ++v)
                    scoreL[(r4 + v) * SL + n] = acc[v];
            }
        }
    }
    __syncthreads();

    // ---- logits: 4-byte LDS lookups ----
    float lg[4];
    #pragma unroll
    for (int j = 0; j < 4; ++j)
        lg[j] = scoreL[(rp4 + j) * SL + ridx[j]] - (1.0f - msk[j]) * 1e31f;

    // ---- max (waves 0..3 rows 0-3; 4..7 rows 4-7) ----
    float mx[4];
    #pragma unroll
    for (int j = 0; j < 4; ++j) mx[j] = lg[j];
    #pragma unroll
    for (int off = 32; off >= 1; off >>= 1) {
        #pragma unroll
        for (int j = 0; j < 4; ++j)
            mx[j] = fmaxf(mx[j], __shfl_xor(mx[j], off, 64));
    }
    if (l == 0) {
        #pragma unroll
        for (int j = 0; j < 4; ++j) wredM[w][j] = mx[j];
    }
    __syncthreads();
    {
        const int wb = rp * 4;
        #pragma unroll
        for (int j = 0; j < 4; ++j)
            mx[j] = fmaxf(fmaxf(wredM[wb][j], wredM[wb+1][j]),
                          fmaxf(wredM[wb+2][j], wredM[wb+3][j]));
    }

    // ---- exp + joint sums S, SL = sum p*(lg-m) ----
    float p[4], s[4], sl[4];
    #pragma unroll
    for (int j = 0; j < 4; ++j) {
        const float z = lg[j] - mx[j];
        p[j]  = __expf(z);
        s[j]  = p[j];
        sl[j] = p[j] * z;
    }
    #pragma unroll
    for (int off = 32; off >= 1; off >>= 1) {
        #pragma unroll
        for (int j = 0; j < 4; ++j) {
            s[j]  += __shfl_xor(s[j],  off, 64);
            sl[j] += __shfl_xor(sl[j], off, 64);
        }
    }
    if (l == 0) {
        #pragma unroll
        for (int j = 0; j < 4; ++j) { wredS[w][j] = s[j]; wredL[w][j] = sl[j]; }
    }
    __syncthreads();
    float S[4], SLs[4];
    {
        const int wb = rp * 4;
        #pragma unroll
        for (int j = 0; j < 4; ++j) {
            S  [j] = wredS[wb][j] + wredS[wb+1][j] + wredS[wb+2][j] + wredS[wb+3][j];
            SLs[j] = wredL[wb][j] + wredL[wb+1][j] + wredL[wb+2][j] + wredL[wb+3][j];
        }
    }

    // ---- outputs ----
    #pragma unroll
    for (int j = 0; j < 4; ++j)
        dist_out[(size_t)(b0 + rp4 + j) * AA + a] = p[j] / S[j];
    if (t == 0) {
        #pragma unroll
        for (int j = 0; j < 4; ++j)
            ent_out[b0 + j] = __logf(S[j]) - SLs[j] / S[j];
    }
    if (t == 256) {
        #pragma unroll
        for (int j = 0; j < 4; ++j)
            ent_out[b0 + 4 + j] = __logf(S[j]) - SLs[j] / S[j];
    }
}

extern "C" void kernel_launch(void* const* d_in, const int* in_sizes, int n_in,
                              void* d_out, int out_size, void* d_ws, size_t ws_size,
                              hipStream_t stream) {
    const int*   e          = (const int*)  d_in[0];
    const int*   q          = (const int*)  d_in[1];
    const float* H          = (const float*)d_in[2];
    const int*   r_space    = (const int*)  d_in[3];
    const float* r_mask     = (const float*)d_in[4];
    const float* entity_emb = (const float*)d_in[5];
    const float* rel_emb    = (const float*)d_in[6];
    const float* W1         = (const float*)d_in[7];
    const float* b1         = (const float*)d_in[8];
    const float* W2         = (const float*)d_in[9];
    const float* b2         = (const float*)d_in[10];

    const int B = in_sizes[0];              // 2048
    float* dist_out = (float*)d_out;                    // [B, 256]
    float* ent_out  = (float*)d_out + (size_t)B * AA;   // [B]
    uint4* wsb      = (uint4*)d_ws;                     // 572 KB packed B-frags

    prep_kernel<<<PREP_T / 256, 256, 0, stream>>>(W1, W2, rel_emb, wsb);
    policy_kernel<<<B / BB, 512, 0, stream>>>(
        e, q, H, r_space, r_mask, entity_emb, rel_emb,
        b1, b2, wsb, dist_out, ent_out);
}